// Round 18
// baseline (163.364 us; speedup 1.0000x reference)
//
#include <hip/hip_runtime.h>
#include <hip/hip_bf16.h>

// B=4, S=1024, D=1024, H=16, d_k=64, MAX_REL=128 (NP=257)
#define NP 257

typedef __attribute__((ext_vector_type(8))) short short8;
typedef __attribute__((ext_vector_type(4))) float f32x4;

__device__ __forceinline__ unsigned short f32_to_bf16(float f) {
    unsigned int u = __float_as_uint(f);
    unsigned int r = (u + 0x7FFFu + ((u >> 16) & 1u)) >> 16;
    return (unsigned short)r;
}
__device__ __forceinline__ float bf16_to_f32(unsigned short u) {
    return __uint_as_float(((unsigned int)u) << 16);
}
__device__ __forceinline__ float bf16_lo(unsigned int u) {
    return __uint_as_float(u << 16);
}
__device__ __forceinline__ float bf16_hi(unsigned int u) {
    return __uint_as_float(u & 0xFFFF0000u);
}

// ---------------- fp32 -> bf16 pack, 8 elems/thread; grid.y selects buffer pair
__global__ __launch_bounds__(256) void cvt_bf16_2(const float* __restrict__ s0,
                                                  unsigned short* __restrict__ d0,
                                                  const float* __restrict__ s1,
                                                  unsigned short* __restrict__ d1,
                                                  int n8)
{
    int i = blockIdx.x * 256 + threadIdx.x;
    if (i >= n8) return;
    const float* src = blockIdx.y ? s1 : s0;
    unsigned short* dst = blockIdx.y ? d1 : d0;
    const float4* s = reinterpret_cast<const float4*>(src) + (size_t)i * 2;
    float4 a = s[0], b = s[1];
    union { unsigned short u[8]; uint4 v; } p;
    p.u[0] = f32_to_bf16(a.x); p.u[1] = f32_to_bf16(a.y);
    p.u[2] = f32_to_bf16(a.z); p.u[3] = f32_to_bf16(a.w);
    p.u[4] = f32_to_bf16(b.x); p.u[5] = f32_to_bf16(b.y);
    p.u[6] = f32_to_bf16(b.z); p.u[7] = f32_to_bf16(b.w);
    reinterpret_cast<uint4*>(dst)[i] = p.v;
}

// ---------------- MFMA projection, both GEMMs in one dispatch (XCD-swizzled).
__global__ __launch_bounds__(256) void proj_mfma(const unsigned short* __restrict__ Xq,
                                                 const unsigned short* __restrict__ Wqb,
                                                 const float* __restrict__ bq,
                                                 unsigned short* __restrict__ outq,
                                                 const unsigned short* __restrict__ Xk,
                                                 const unsigned short* __restrict__ Wkb,
                                                 const float* __restrict__ bk,
                                                 unsigned short* __restrict__ outk)
{
    __shared__ unsigned short LDSb[16384];       // 32 KB: staging As|Bs; epilogue C-tile
    unsigned short* As = LDSb;
    unsigned short* Bs = LDSb + 8192;

    const int bid = blockIdx.x;                  // 0..511
    const int lid = (bid & 7) * 64 + (bid >> 3); // logical id, chunked per XCD
    const int bnb = lid & 7;
    const int bmb = (lid >> 3) & 31;
    const int z   = lid >> 8;

    const unsigned short* Xb = z ? Xk : Xq;
    const unsigned short* Wb = z ? Wkb : Wqb;
    const float* bias        = z ? bk : bq;
    unsigned short* outb     = z ? outk : outq;

    const int tid = threadIdx.x;
    const int lane = tid & 63;
    const int w = tid >> 6;
    const int wi = w >> 1, wj = w & 1;
    const int bm = bmb * 128, bn = bnb * 128;
    const int r15 = lane & 15, g = lane >> 4;

    f32x4 acc[4][4];
    #pragma unroll
    for (int i = 0; i < 4; ++i)
        #pragma unroll
        for (int j = 0; j < 4; ++j) acc[i][j] = (f32x4){0.f, 0.f, 0.f, 0.f};

    size_t offA[4], offB[4];
    #pragma unroll
    for (int it = 0; it < 4; ++it) {
        int f = it * 256 + tid, row = f >> 3, cl = (f & 7) ^ (row & 7);
        offA[it] = (size_t)(bm + row) * 1024 + cl * 8;
        offB[it] = (size_t)(bn + row) * 1024 + cl * 8;
    }
    const int ldsbase = w * 512;

    for (int kt = 0; kt < 16; ++kt) {
        const int k0 = kt * 64;
        #pragma unroll
        for (int it = 0; it < 4; ++it)
            __builtin_amdgcn_global_load_lds(
                (const __attribute__((address_space(1))) void*)(Xb + offA[it] + k0),
                (__attribute__((address_space(3))) void*)(As + it * 2048 + ldsbase), 16, 0, 0);
        #pragma unroll
        for (int it = 0; it < 4; ++it)
            __builtin_amdgcn_global_load_lds(
                (const __attribute__((address_space(1))) void*)(Wb + offB[it] + k0),
                (__attribute__((address_space(3))) void*)(Bs + it * 2048 + ldsbase), 16, 0, 0);
        __syncthreads();

        #pragma unroll
        for (int kk = 0; kk < 2; ++kk) {
            const int c = kk * 4 + g;
            short8 a[4], bfr[4];
            #pragma unroll
            for (int ti = 0; ti < 4; ++ti) {
                const int ra = wi * 64 + ti * 16 + r15;
                a[ti] = *(const short8*)&As[(ra * 8 + (c ^ (ra & 7))) * 8];
            }
            #pragma unroll
            for (int tj = 0; tj < 4; ++tj) {
                const int rb = wj * 64 + tj * 16 + r15;
                bfr[tj] = *(const short8*)&Bs[(rb * 8 + (c ^ (rb & 7))) * 8];
            }
            #pragma unroll
            for (int ti = 0; ti < 4; ++ti)
                #pragma unroll
                for (int tj = 0; tj < 4; ++tj)
                    acc[ti][tj] = __builtin_amdgcn_mfma_f32_16x16x32_bf16(a[ti], bfr[tj], acc[ti][tj], 0, 0, 0);
        }
        __syncthreads();
    }

    // epilogue: stage bf16 C-tile in LDSb (chunk-XOR swizzled), coalesced stores
    #pragma unroll
    for (int tj = 0; tj < 4; ++tj) {
        const int ncol = wj * 64 + tj * 16 + r15;
        const float bv = bias[bn + ncol];
        #pragma unroll
        for (int ti = 0; ti < 4; ++ti) {
            const int mrow = wi * 64 + ti * 16 + (g << 2);
            #pragma unroll
            for (int r = 0; r < 4; ++r) {
                const int row = mrow + r;
                const int idx = row * 128 + ((((ncol >> 3) ^ (row & 7)) << 3) | (ncol & 7));
                LDSb[idx] = f32_to_bf16(acc[ti][tj][r] + bv);
            }
        }
    }
    __syncthreads();

    #pragma unroll
    for (int it2 = 0; it2 < 8; ++it2) {
        const int row = it2 * 16 + (tid >> 4);
        const int cc = tid & 15;
        const uint4 v = *reinterpret_cast<const uint4*>(
            &LDSb[row * 128 + ((cc ^ (row & 7)) << 3)]);
        *reinterpret_cast<uint4*>(&outb[(size_t)(bm + row) * 1024 + bn + cc * 8]) = v;
    }
}

// ---------------- biasrow: per (b,i) fused qmean + reldot + mask -> bf16 bias row
__global__ __launch_bounds__(256) void biasrow(const unsigned short* __restrict__ qb,
                                               const float* __restrict__ relk,
                                               const int* __restrict__ mask,
                                               unsigned short* __restrict__ biasbf)
{
    __shared__ __align__(16) float qm[64];
    __shared__ float rd[NP];
    const int bi = blockIdx.x;                  // b*1024 + i, 4096 blocks
    const int i = bi & 1023;
    const int t = threadIdx.x;
    if (t < 64) {
        const unsigned short* qrow = qb + ((size_t)bi << 10);
        float s = 0.f;
        #pragma unroll
        for (int h2 = 0; h2 < 16; ++h2) s += bf16_to_f32(qrow[h2 * 64 + t]);
        qm[t] = s * 0.0625f;
    }
    __syncthreads();
    const float4* qm4 = reinterpret_cast<const float4*>(qm);
    for (int p = t; p < NP; p += 256) {
        const float4* rk4 = reinterpret_cast<const float4*>(relk + (size_t)p * 64);
        float s0 = 0.f, s1 = 0.f, s2 = 0.f, s3 = 0.f;
        #pragma unroll
        for (int d4 = 0; d4 < 16; ++d4) {
            float4 a = qm4[d4];
            float4 b = rk4[d4];
            s0 = fmaf(a.x, b.x, s0);
            s1 = fmaf(a.y, b.y, s1);
            s2 = fmaf(a.z, b.z, s2);
            s3 = fmaf(a.w, b.w, s3);
        }
        rd[p] = (s0 + s1 + s2 + s3) * 0.125f;
    }
    __syncthreads();

    const int4 mk = reinterpret_cast<const int4*>(mask + ((size_t)bi << 10))[t];
    const int j0 = t * 4;
    int d;
    float v0, v1, v2, v3;
    d = min(max(j0 + 0 - i, -128), 128); v0 = mk.x ? rd[d + 128] : -1e9f;
    d = min(max(j0 + 1 - i, -128), 128); v1 = mk.y ? rd[d + 128] : -1e9f;
    d = min(max(j0 + 2 - i, -128), 128); v2 = mk.z ? rd[d + 128] : -1e9f;
    d = min(max(j0 + 3 - i, -128), 128); v3 = mk.w ? rd[d + 128] : -1e9f;
    uint2 pk;
    pk.x = f32_to_bf16(v0) | ((unsigned int)f32_to_bf16(v1) << 16);
    pk.y = f32_to_bf16(v2) | ((unsigned int)f32_to_bf16(v3) << 16);
    *reinterpret_cast<uint2*>(biasbf + ((size_t)bi << 10) + j0) = pk;
}

// ---------------- attn11: LDS-staged K+bias, XCD-chunked grid (R16 winner)
__global__ __launch_bounds__(256) void attn11(const unsigned short* __restrict__ qb,
                                              const unsigned short* __restrict__ kb,
                                              const unsigned short* __restrict__ biasbf,
                                              float* __restrict__ out)
{
    __shared__ unsigned short Ks[8192];           // 128 j-rows x 8 chunks x 8 bf16
    __shared__ unsigned short Bt[2048];           // 16 i-rows x 16 chunks x 8 bf16
    __shared__ unsigned short e_lds[16 * 1024];   // 32 KB
    __shared__ float redsum[4][16];

    const int bid = blockIdx.x;                   // 0..4095
    const int lid = (bid & 7) * 512 + (bid >> 3);
    const int i0 = (lid & 63) * 16;
    const int h  = (lid >> 6) & 15;
    const int b  = lid >> 10;

    const int tid = threadIdx.x, lane = tid & 63, w = tid >> 6;
    const int r15 = lane & 15, g = lane >> 4;
    const size_t qkbase = ((size_t)b << 20) + h * 64;

    const unsigned short* qp = qb + qkbase + (size_t)(i0 + r15) * 1024 + 8 * g;
    short8 qf0 = *(const short8*)qp;
    short8 qf1 = *(const short8*)(qp + 32);

    size_t offK[4];
    #pragma unroll
    for (int it = 0; it < 4; ++it) {
        int f = it * 256 + tid, row = f >> 3, cl = (f & 7) ^ (row & 7);
        offK[it] = qkbase + (size_t)row * 1024 + cl * 8;   // + (jtile)*1024
    }
    const int brow = tid >> 4, bchunk = tid & 15;
    const size_t offBt = (((size_t)(b * 1024 + i0 + brow)) << 10) + (size_t)((bchunk ^ (brow & 7)) * 8);
    const int ldsKbase = w * 512;
    const int ldsBtbase = w * 512;

    float ps = 0.f;

    for (int t = 0; t < 8; ++t) {
        const int jtile = t * 128;
        #pragma unroll
        for (int it = 0; it < 4; ++it)
            __builtin_amdgcn_global_load_lds(
                (const __attribute__((address_space(1))) void*)(kb + offK[it] + (size_t)jtile * 1024),
                (__attribute__((address_space(3))) void*)(Ks + it * 2048 + ldsKbase), 16, 0, 0);
        __builtin_amdgcn_global_load_lds(
            (const __attribute__((address_space(1))) void*)(biasbf + offBt + jtile),
            (__attribute__((address_space(3))) void*)(Bt + ldsBtbase), 16, 0, 0);
        __syncthreads();

        #pragma unroll
        for (int s = 0; s < 2; ++s) {
            const int js = (w * 2 + s) * 16;       // local j sub-tile base
            const int jr = js + r15;               // this lane's K row in tile
            short8 kf0 = *(const short8*)&Ks[(jr * 8 + (g ^ (jr & 7))) * 8];
            short8 kf1 = *(const short8*)&Ks[(jr * 8 + ((g + 4) ^ (jr & 7))) * 8];
            f32x4 acc = (f32x4){0.f, 0.f, 0.f, 0.f};
            acc = __builtin_amdgcn_mfma_f32_16x16x32_bf16(kf0, qf0, acc, 0, 0, 0);
            acc = __builtin_amdgcn_mfma_f32_16x16x32_bf16(kf1, qf1, acc, 0, 0, 0);

            const int jloc = js + (g << 2);        // lane's first col, tile-local
            const int cj = jloc >> 3;
            const uint2 bv = *reinterpret_cast<const uint2*>(
                &Bt[(r15 * 16 + (cj ^ (r15 & 7))) * 8 + (g & 1) * 4]);

            const float e0 = __expf(fmaf(acc[0], 0.125f, bf16_lo(bv.x)));
            const float e1 = __expf(fmaf(acc[1], 0.125f, bf16_hi(bv.x)));
            const float e2 = __expf(fmaf(acc[2], 0.125f, bf16_lo(bv.y)));
            const float e3 = __expf(fmaf(acc[3], 0.125f, bf16_hi(bv.y)));
            ps += (e0 + e1) + (e2 + e3);

            const unsigned int u0 = f32_to_bf16(e0) | ((unsigned int)f32_to_bf16(e1) << 16);
            const unsigned int u1 = f32_to_bf16(e2) | ((unsigned int)f32_to_bf16(e3) << 16);
            const int jglob = jtile + jloc;
            const int us = r15 * 1024 + ((jglob + r15 * 4) & 1023);
            *reinterpret_cast<uint2*>(&e_lds[us]) = make_uint2(u0, u1);
        }
        __syncthreads();
    }

    ps += __shfl_xor(ps, 16, 64);
    ps += __shfl_xor(ps, 32, 64);
    if (lane < 16) redsum[w][r15] = ps;
    __syncthreads();

    #pragma unroll
    for (int rr = 0; rr < 4; ++rr) {
        const int rl = w * 4 + rr;
        const float inv = 1.0f / (redsum[0][rl] + redsum[1][rl] + redsum[2][rl] + redsum[3][rl]);
        float* op = out + (((size_t)((b * 16 + h) * 1024 + i0 + rl)) << 10);
        #pragma unroll
        for (int n = 0; n < 4; ++n) {
            const int c = n * 256 + lane * 4;
            const int us = rl * 1024 + ((c + rl * 4) & 1023);
            uint2 u = *reinterpret_cast<const uint2*>(&e_lds[us]);
            f32x4 v;
            v[0] = bf16_to_f32((unsigned short)(u.x & 0xFFFFu)) * inv;
            v[1] = bf16_to_f32((unsigned short)(u.x >> 16)) * inv;
            v[2] = bf16_to_f32((unsigned short)(u.y & 0xFFFFu)) * inv;
            v[3] = bf16_to_f32((unsigned short)(u.y >> 16)) * inv;
            __builtin_nontemporal_store(v, reinterpret_cast<f32x4*>(op + c));
        }
    }
}

extern "C" void kernel_launch(void* const* d_in, const int* in_sizes, int n_in,
                              void* d_out, int out_size, void* d_ws, size_t ws_size,
                              hipStream_t stream) {
    const float* query = (const float*)d_in[0];
    const float* key   = (const float*)d_in[1];
    const int*   mask  = (const int*)d_in[2];
    const float* Wq    = (const float*)d_in[3];
    const float* bq    = (const float*)d_in[4];
    const float* Wk    = (const float*)d_in[5];
    const float* bk    = (const float*)d_in[6];
    const float* relk  = (const float*)d_in[7];

    char* ws = (char*)d_ws;
    unsigned short* qB     = (unsigned short*)(ws);
    unsigned short* kB     = (unsigned short*)(ws + (8u  << 20));
    unsigned short* queryb = (unsigned short*)(ws + (16u << 20));
    unsigned short* keyb   = (unsigned short*)(ws + (24u << 20));
    unsigned short* Wqb    = (unsigned short*)(ws + (32u << 20));
    unsigned short* Wkb    = (unsigned short*)(ws + (34u << 20));
    unsigned short* biasbf = (unsigned short*)(ws + (36u << 20));
    float*          out    = (float*)d_out;

    cvt_bf16_2<<<dim3(2048, 2), 256, 0, stream>>>(query, queryb, key, keyb, 524288);
    cvt_bf16_2<<<dim3(512, 2),  256, 0, stream>>>(Wq, Wqb, Wk, Wkb, 131072);

    // A/B measurement round (R13 pattern): proj dispatched twice (idempotent).
    // dur delta vs R17 = proj's absolute cost.
    proj_mfma<<<512, 256, 0, stream>>>(queryb, Wqb, bq, qB,
                                       keyb,   Wkb, bk, kB);
    proj_mfma<<<512, 256, 0, stream>>>(queryb, Wqb, bq, qB,
                                       keyb,   Wkb, bk, kB);

    biasrow<<<4096, 256, 0, stream>>>(qB, relk, mask, biasbf);

    attn11<<<4096, 256, 0, stream>>>(qB, kB, biasbf, out);
}

// Round 19
// 138.628 us; speedup vs baseline: 1.1784x; 1.1784x over previous
//
#include <hip/hip_runtime.h>
#include <hip/hip_bf16.h>

// B=4, S=1024, D=1024, H=16, d_k=64, MAX_REL=128 (NP=257)
#define NP 257

typedef __attribute__((ext_vector_type(8))) short short8;
typedef __attribute__((ext_vector_type(4))) float f32x4;

__device__ __forceinline__ unsigned short f32_to_bf16(float f) {
    unsigned int u = __float_as_uint(f);
    unsigned int r = (u + 0x7FFFu + ((u >> 16) & 1u)) >> 16;
    return (unsigned short)r;
}
__device__ __forceinline__ float bf16_to_f32(unsigned short u) {
    return __uint_as_float(((unsigned int)u) << 16);
}
__device__ __forceinline__ float bf16_lo(unsigned int u) {
    return __uint_as_float(u << 16);
}
__device__ __forceinline__ float bf16_hi(unsigned int u) {
    return __uint_as_float(u & 0xFFFF0000u);
}

// ---------------- fp32 -> bf16 pack, ALL four buffers in one dispatch.
// Ranges (in 8-elem slots): query [0,524288), key [524288,1048576),
// Wq [1048576,1179648), Wk [1179648,1310720). 5120 blocks.
__global__ __launch_bounds__(256) void cvt_all(const float* __restrict__ query,
                                               unsigned short* __restrict__ queryb,
                                               const float* __restrict__ key,
                                               unsigned short* __restrict__ keyb,
                                               const float* __restrict__ Wq,
                                               unsigned short* __restrict__ Wqb,
                                               const float* __restrict__ Wk,
                                               unsigned short* __restrict__ Wkb)
{
    int i = blockIdx.x * 256 + threadIdx.x;      // slot id, < 1310720
    const float* src;
    unsigned short* dst;
    int o;
    if (i < 524288)        { src = query; dst = queryb; o = i; }
    else if (i < 1048576)  { src = key;   dst = keyb;   o = i - 524288; }
    else if (i < 1179648)  { src = Wq;    dst = Wqb;    o = i - 1048576; }
    else                   { src = Wk;    dst = Wkb;    o = i - 1179648; }
    const float4* s = reinterpret_cast<const float4*>(src) + (size_t)o * 2;
    float4 a = s[0], b = s[1];
    union { unsigned short u[8]; uint4 v; } p;
    p.u[0] = f32_to_bf16(a.x); p.u[1] = f32_to_bf16(a.y);
    p.u[2] = f32_to_bf16(a.z); p.u[3] = f32_to_bf16(a.w);
    p.u[4] = f32_to_bf16(b.x); p.u[5] = f32_to_bf16(b.y);
    p.u[6] = f32_to_bf16(b.z); p.u[7] = f32_to_bf16(b.w);
    reinterpret_cast<uint4*>(dst)[o] = p.v;
}

// ---------------- MFMA projection, both GEMMs in one dispatch (XCD-swizzled).
// Measured (R18 A/B): 22.5 us for the pair.
__global__ __launch_bounds__(256) void proj_mfma(const unsigned short* __restrict__ Xq,
                                                 const unsigned short* __restrict__ Wqb,
                                                 const float* __restrict__ bq,
                                                 unsigned short* __restrict__ outq,
                                                 const unsigned short* __restrict__ Xk,
                                                 const unsigned short* __restrict__ Wkb,
                                                 const float* __restrict__ bk,
                                                 unsigned short* __restrict__ outk)
{
    __shared__ unsigned short LDSb[16384];       // 32 KB: staging As|Bs; epilogue C-tile
    unsigned short* As = LDSb;
    unsigned short* Bs = LDSb + 8192;

    const int bid = blockIdx.x;                  // 0..511
    const int lid = (bid & 7) * 64 + (bid >> 3); // logical id, chunked per XCD
    const int bnb = lid & 7;
    const int bmb = (lid >> 3) & 31;
    const int z   = lid >> 8;

    const unsigned short* Xb = z ? Xk : Xq;
    const unsigned short* Wb = z ? Wkb : Wqb;
    const float* bias        = z ? bk : bq;
    unsigned short* outb     = z ? outk : outq;

    const int tid = threadIdx.x;
    const int lane = tid & 63;
    const int w = tid >> 6;
    const int wi = w >> 1, wj = w & 1;
    const int bm = bmb * 128, bn = bnb * 128;
    const int r15 = lane & 15, g = lane >> 4;

    f32x4 acc[4][4];
    #pragma unroll
    for (int i = 0; i < 4; ++i)
        #pragma unroll
        for (int j = 0; j < 4; ++j) acc[i][j] = (f32x4){0.f, 0.f, 0.f, 0.f};

    size_t offA[4], offB[4];
    #pragma unroll
    for (int it = 0; it < 4; ++it) {
        int f = it * 256 + tid, row = f >> 3, cl = (f & 7) ^ (row & 7);
        offA[it] = (size_t)(bm + row) * 1024 + cl * 8;
        offB[it] = (size_t)(bn + row) * 1024 + cl * 8;
    }
    const int ldsbase = w * 512;

    for (int kt = 0; kt < 16; ++kt) {
        const int k0 = kt * 64;
        #pragma unroll
        for (int it = 0; it < 4; ++it)
            __builtin_amdgcn_global_load_lds(
                (const __attribute__((address_space(1))) void*)(Xb + offA[it] + k0),
                (__attribute__((address_space(3))) void*)(As + it * 2048 + ldsbase), 16, 0, 0);
        #pragma unroll
        for (int it = 0; it < 4; ++it)
            __builtin_amdgcn_global_load_lds(
                (const __attribute__((address_space(1))) void*)(Wb + offB[it] + k0),
                (__attribute__((address_space(3))) void*)(Bs + it * 2048 + ldsbase), 16, 0, 0);
        __syncthreads();

        #pragma unroll
        for (int kk = 0; kk < 2; ++kk) {
            const int c = kk * 4 + g;
            short8 a[4], bfr[4];
            #pragma unroll
            for (int ti = 0; ti < 4; ++ti) {
                const int ra = wi * 64 + ti * 16 + r15;
                a[ti] = *(const short8*)&As[(ra * 8 + (c ^ (ra & 7))) * 8];
            }
            #pragma unroll
            for (int tj = 0; tj < 4; ++tj) {
                const int rb = wj * 64 + tj * 16 + r15;
                bfr[tj] = *(const short8*)&Bs[(rb * 8 + (c ^ (rb & 7))) * 8];
            }
            #pragma unroll
            for (int ti = 0; ti < 4; ++ti)
                #pragma unroll
                for (int tj = 0; tj < 4; ++tj)
                    acc[ti][tj] = __builtin_amdgcn_mfma_f32_16x16x32_bf16(a[ti], bfr[tj], acc[ti][tj], 0, 0, 0);
        }
        __syncthreads();
    }

    // epilogue: stage bf16 C-tile in LDSb (chunk-XOR swizzled), coalesced stores
    #pragma unroll
    for (int tj = 0; tj < 4; ++tj) {
        const int ncol = wj * 64 + tj * 16 + r15;
        const float bv = bias[bn + ncol];
        #pragma unroll
        for (int ti = 0; ti < 4; ++ti) {
            const int mrow = wi * 64 + ti * 16 + (g << 2);
            #pragma unroll
            for (int r = 0; r < 4; ++r) {
                const int row = mrow + r;
                const int idx = row * 128 + ((((ncol >> 3) ^ (row & 7)) << 3) | (ncol & 7));
                LDSb[idx] = f32_to_bf16(acc[ti][tj][r] + bv);
            }
        }
    }
    __syncthreads();

    #pragma unroll
    for (int it2 = 0; it2 < 8; ++it2) {
        const int row = it2 * 16 + (tid >> 4);
        const int cc = tid & 15;
        const uint4 v = *reinterpret_cast<const uint4*>(
            &LDSb[row * 128 + ((cc ^ (row & 7)) << 3)]);
        *reinterpret_cast<uint4*>(&outb[(size_t)(bm + row) * 1024 + bn + cc * 8]) = v;
    }
}

// ---------------- biasrow: per (b,i) fused qmean + reldot + mask -> bf16 bias row
__global__ __launch_bounds__(256) void biasrow(const unsigned short* __restrict__ qb,
                                               const float* __restrict__ relk,
                                               const int* __restrict__ mask,
                                               unsigned short* __restrict__ biasbf)
{
    __shared__ __align__(16) float qm[64];
    __shared__ float rd[NP];
    const int bi = blockIdx.x;                  // b*1024 + i, 4096 blocks
    const int i = bi & 1023;
    const int t = threadIdx.x;
    if (t < 64) {
        const unsigned short* qrow = qb + ((size_t)bi << 10);
        float s = 0.f;
        #pragma unroll
        for (int h2 = 0; h2 < 16; ++h2) s += bf16_to_f32(qrow[h2 * 64 + t]);
        qm[t] = s * 0.0625f;
    }
    __syncthreads();
    const float4* qm4 = reinterpret_cast<const float4*>(qm);
    for (int p = t; p < NP; p += 256) {
        const float4* rk4 = reinterpret_cast<const float4*>(relk + (size_t)p * 64);
        float s0 = 0.f, s1 = 0.f, s2 = 0.f, s3 = 0.f;
        #pragma unroll
        for (int d4 = 0; d4 < 16; ++d4) {
            float4 a = qm4[d4];
            float4 b = rk4[d4];
            s0 = fmaf(a.x, b.x, s0);
            s1 = fmaf(a.y, b.y, s1);
            s2 = fmaf(a.z, b.z, s2);
            s3 = fmaf(a.w, b.w, s3);
        }
        rd[p] = (s0 + s1 + s2 + s3) * 0.125f;
    }
    __syncthreads();

    const int4 mk = reinterpret_cast<const int4*>(mask + ((size_t)bi << 10))[t];
    const int j0 = t * 4;
    int d;
    float v0, v1, v2, v3;
    d = min(max(j0 + 0 - i, -128), 128); v0 = mk.x ? rd[d + 128] : -1e9f;
    d = min(max(j0 + 1 - i, -128), 128); v1 = mk.y ? rd[d + 128] : -1e9f;
    d = min(max(j0 + 2 - i, -128), 128); v2 = mk.z ? rd[d + 128] : -1e9f;
    d = min(max(j0 + 3 - i, -128), 128); v3 = mk.w ? rd[d + 128] : -1e9f;
    uint2 pk;
    pk.x = f32_to_bf16(v0) | ((unsigned int)f32_to_bf16(v1) << 16);
    pk.y = f32_to_bf16(v2) | ((unsigned int)f32_to_bf16(v3) << 16);
    *reinterpret_cast<uint2*>(biasbf + ((size_t)bi << 10) + j0) = pk;
}

// ---------------- attn11: LDS-staged K+bias, XCD-chunked grid (R16 winner, ~65us)
__global__ __launch_bounds__(256) void attn11(const unsigned short* __restrict__ qb,
                                              const unsigned short* __restrict__ kb,
                                              const unsigned short* __restrict__ biasbf,
                                              float* __restrict__ out)
{
    __shared__ unsigned short Ks[8192];           // 128 j-rows x 8 chunks x 8 bf16
    __shared__ unsigned short Bt[2048];           // 16 i-rows x 16 chunks x 8 bf16
    __shared__ unsigned short e_lds[16 * 1024];   // 32 KB
    __shared__ float redsum[4][16];

    const int bid = blockIdx.x;                   // 0..4095
    const int lid = (bid & 7) * 512 + (bid >> 3);
    const int i0 = (lid & 63) * 16;
    const int h  = (lid >> 6) & 15;
    const int b  = lid >> 10;

    const int tid = threadIdx.x, lane = tid & 63, w = tid >> 6;
    const int r15 = lane & 15, g = lane >> 4;
    const size_t qkbase = ((size_t)b << 20) + h * 64;

    const unsigned short* qp = qb + qkbase + (size_t)(i0 + r15) * 1024 + 8 * g;
    short8 qf0 = *(const short8*)qp;
    short8 qf1 = *(const short8*)(qp + 32);

    size_t offK[4];
    #pragma unroll
    for (int it = 0; it < 4; ++it) {
        int f = it * 256 + tid, row = f >> 3, cl = (f & 7) ^ (row & 7);
        offK[it] = qkbase + (size_t)row * 1024 + cl * 8;   // + (jtile)*1024
    }
    const int brow = tid >> 4, bchunk = tid & 15;
    const size_t offBt = (((size_t)(b * 1024 + i0 + brow)) << 10) + (size_t)((bchunk ^ (brow & 7)) * 8);
    const int ldsKbase = w * 512;
    const int ldsBtbase = w * 512;

    float ps = 0.f;

    for (int t = 0; t < 8; ++t) {
        const int jtile = t * 128;
        #pragma unroll
        for (int it = 0; it < 4; ++it)
            __builtin_amdgcn_global_load_lds(
                (const __attribute__((address_space(1))) void*)(kb + offK[it] + (size_t)jtile * 1024),
                (__attribute__((address_space(3))) void*)(Ks + it * 2048 + ldsKbase), 16, 0, 0);
        __builtin_amdgcn_global_load_lds(
            (const __attribute__((address_space(1))) void*)(biasbf + offBt + jtile),
            (__attribute__((address_space(3))) void*)(Bt + ldsBtbase), 16, 0, 0);
        __syncthreads();

        #pragma unroll
        for (int s = 0; s < 2; ++s) {
            const int js = (w * 2 + s) * 16;       // local j sub-tile base
            const int jr = js + r15;               // this lane's K row in tile
            short8 kf0 = *(const short8*)&Ks[(jr * 8 + (g ^ (jr & 7))) * 8];
            short8 kf1 = *(const short8*)&Ks[(jr * 8 + ((g + 4) ^ (jr & 7))) * 8];
            f32x4 acc = (f32x4){0.f, 0.f, 0.f, 0.f};
            acc = __builtin_amdgcn_mfma_f32_16x16x32_bf16(kf0, qf0, acc, 0, 0, 0);
            acc = __builtin_amdgcn_mfma_f32_16x16x32_bf16(kf1, qf1, acc, 0, 0, 0);

            const int jloc = js + (g << 2);        // lane's first col, tile-local
            const int cj = jloc >> 3;
            const uint2 bv = *reinterpret_cast<const uint2*>(
                &Bt[(r15 * 16 + (cj ^ (r15 & 7))) * 8 + (g & 1) * 4]);

            const float e0 = __expf(fmaf(acc[0], 0.125f, bf16_lo(bv.x)));
            const float e1 = __expf(fmaf(acc[1], 0.125f, bf16_hi(bv.x)));
            const float e2 = __expf(fmaf(acc[2], 0.125f, bf16_lo(bv.y)));
            const float e3 = __expf(fmaf(acc[3], 0.125f, bf16_hi(bv.y)));
            ps += (e0 + e1) + (e2 + e3);

            const unsigned int u0 = f32_to_bf16(e0) | ((unsigned int)f32_to_bf16(e1) << 16);
            const unsigned int u1 = f32_to_bf16(e2) | ((unsigned int)f32_to_bf16(e3) << 16);
            const int jglob = jtile + jloc;
            const int us = r15 * 1024 + ((jglob + r15 * 4) & 1023);
            *reinterpret_cast<uint2*>(&e_lds[us]) = make_uint2(u0, u1);
        }
        __syncthreads();
    }

    ps += __shfl_xor(ps, 16, 64);
    ps += __shfl_xor(ps, 32, 64);
    if (lane < 16) redsum[w][r15] = ps;
    __syncthreads();

    #pragma unroll
    for (int rr = 0; rr < 4; ++rr) {
        const int rl = w * 4 + rr;
        const float inv = 1.0f / (redsum[0][rl] + redsum[1][rl] + redsum[2][rl] + redsum[3][rl]);
        float* op = out + (((size_t)((b * 16 + h) * 1024 + i0 + rl)) << 10);
        #pragma unroll
        for (int n = 0; n < 4; ++n) {
            const int c = n * 256 + lane * 4;
            const int us = rl * 1024 + ((c + rl * 4) & 1023);
            uint2 u = *reinterpret_cast<const uint2*>(&e_lds[us]);
            f32x4 v;
            v[0] = bf16_to_f32((unsigned short)(u.x & 0xFFFFu)) * inv;
            v[1] = bf16_to_f32((unsigned short)(u.x >> 16)) * inv;
            v[2] = bf16_to_f32((unsigned short)(u.y & 0xFFFFu)) * inv;
            v[3] = bf16_to_f32((unsigned short)(u.y >> 16)) * inv;
            __builtin_nontemporal_store(v, reinterpret_cast<f32x4*>(op + c));
        }
    }
}

extern "C" void kernel_launch(void* const* d_in, const int* in_sizes, int n_in,
                              void* d_out, int out_size, void* d_ws, size_t ws_size,
                              hipStream_t stream) {
    const float* query = (const float*)d_in[0];
    const float* key   = (const float*)d_in[1];
    const int*   mask  = (const int*)d_in[2];
    const float* Wq    = (const float*)d_in[3];
    const float* bq    = (const float*)d_in[4];
    const float* Wk    = (const float*)d_in[5];
    const float* bk    = (const float*)d_in[6];
    const float* relk  = (const float*)d_in[7];

    char* ws = (char*)d_ws;
    unsigned short* qB     = (unsigned short*)(ws);
    unsigned short* kB     = (unsigned short*)(ws + (8u  << 20));
    unsigned short* queryb = (unsigned short*)(ws + (16u << 20));
    unsigned short* keyb   = (unsigned short*)(ws + (24u << 20));
    unsigned short* Wqb    = (unsigned short*)(ws + (32u << 20));
    unsigned short* Wkb    = (unsigned short*)(ws + (34u << 20));
    unsigned short* biasbf = (unsigned short*)(ws + (36u << 20));
    float*          out    = (float*)d_out;

    // 4 dispatches = minimum given the dependency chain cvt -> proj -> biasrow -> attn
    cvt_all<<<5120, 256, 0, stream>>>(query, queryb, key, keyb, Wq, Wqb, Wk, Wkb);

    proj_mfma<<<512, 256, 0, stream>>>(queryb, Wqb, bq, qB,
                                       keyb,   Wkb, bk, kB);

    biasrow<<<4096, 256, 0, stream>>>(qB, relk, mask, biasbf);

    attn11<<<4096, 256, 0, stream>>>(qB, kB, biasbf, out);
}